// Round 1
// baseline (641.502 us; speedup 1.0000x reference)
//
#include <hip/hip_runtime.h>

typedef unsigned short u16;
typedef short bf16x8 __attribute__((ext_vector_type(8)));
typedef float f32x4 __attribute__((ext_vector_type(4)));

__device__ inline u16 f2bf(float f) {
  unsigned u = __float_as_uint(f);
  u += 0x7fff + ((u >> 16) & 1);
  return (u16)(u >> 16);
}

__device__ inline void gl_lds16(const u16* g, u16* l) {
  __builtin_amdgcn_global_load_lds((const __attribute__((address_space(1))) void*)g,
                                   (__attribute__((address_space(3))) void*)l, 16, 0, 0);
}

// ---------------- prep kernels ----------------

__global__ __launch_bounds__(256) void cvt_bf16(const float* __restrict__ in,
                                                u16* __restrict__ outp, int n) {
  int i = blockIdx.x * 256 + threadIdx.x;
  if (i < n) outp[i] = f2bf(in[i]);
}

// W2p[d][h] = sum_c Ww[d][c] * W2[c][h]  (d<256, h<512); b2p[d] = sum_c Ww[d][c]*b2[c]
__global__ __launch_bounds__(256) void w2p_kernel(const float* __restrict__ Ww,
                                                  const float* __restrict__ W2,
                                                  const float* __restrict__ b2,
                                                  u16* __restrict__ W2p,
                                                  float* __restrict__ b2p) {
  int g = blockIdx.x * 256 + threadIdx.x;  // 131072 threads
  int d = g >> 9, h = g & 511;
  float s = 0.f;
  for (int c = 0; c < 256; c++) s += Ww[d * 256 + c] * W2[c * 512 + h];
  W2p[g] = f2bf(s);
  if (g < 256) {
    float t = 0.f;
    for (int c = 0; c < 256; c++) t += Ww[g * 256 + c] * b2[c];
    b2p[g] = t;
  }
}

// in: [1024 b][256 c][64 p] fp32  ->  out: [64 p][1024 b][256 c] bf16
__global__ __launch_bounds__(256) void transpose_cvt(const float* __restrict__ in,
                                                     u16* __restrict__ outp) {
  const int b = blockIdx.x;
  const int tid = threadIdx.x;
  const float4* in4 = (const float4*)in + (size_t)b * 4096;
  u16* ob = outp + (size_t)b * 256;
  #pragma unroll
  for (int i = 0; i < 16; i++) {
    int local = i * 256 + tid;
    int c = local >> 4;
    int p4 = (local & 15) << 2;
    float4 v = in4[local];
    ob[((size_t)(p4 + 0) << 18) + c] = f2bf(v.x);
    ob[((size_t)(p4 + 1) << 18) + c] = f2bf(v.y);
    ob[((size_t)(p4 + 2) << 18) + c] = f2bf(v.z);
    ob[((size_t)(p4 + 3) << 18) + c] = f2bf(v.w);
  }
}

// ---------------- generic bf16 GEMM: C = epi(A1@B1^T + A2@B2^T + bias) ----------------
// A: [M][K] bf16 row-major (stride K), B: [N][K] bf16 row-major (stride K).
// 128x128 tile, BK=64, 256 threads (4 waves, 2x2 of 64x64), 16x16x32 MFMA.
__global__ __launch_bounds__(256, 3)
void gemm_bt(const u16* __restrict__ A1, const u16* __restrict__ B1, int K1len,
             const u16* __restrict__ A2, const u16* __restrict__ B2, int K2len,
             const float* __restrict__ bias, u16* __restrict__ C, int N, int relu) {
  __shared__ u16 As[128 * 64];
  __shared__ u16 Bs[128 * 64];
  const int tid = threadIdx.x;
  const int lane = tid & 63;
  const int wave = tid >> 6;
  const int wm = wave & 1;
  const int wn = wave >> 1;
  const int m0 = blockIdx.y * 128;
  const int n0 = blockIdx.x * 128;
  const int q = lane >> 4;
  const int l15 = lane & 15;

  f32x4 acc[4][4];
  #pragma unroll
  for (int i = 0; i < 4; i++)
    #pragma unroll
    for (int j = 0; j < 4; j++) acc[i][j] = (f32x4)(0.0f);

  for (int seg = 0; seg < 2; seg++) {
    const u16* A = seg ? A2 : A1;
    const u16* B = seg ? B2 : B1;
    const int K = seg ? K2len : K1len;
    const int nkt = K >> 6;
    for (int kt = 0; kt < nkt; kt++) {
      // stage 128x64 A and B tiles; LDS chunk (row, c) holds global chunk c^(row&7)
      #pragma unroll
      for (int c = 0; c < 4; c++) {
        int chunk = c * 256 + tid;     // 0..1023 ; 8 chunks of 16B per row
        int row = chunk >> 3;
        int cg = (chunk & 7) ^ (row & 7);
        gl_lds16(A + (size_t)(m0 + row) * K + kt * 64 + cg * 8, &As[chunk * 8]);
        gl_lds16(B + (size_t)(n0 + row) * K + kt * 64 + cg * 8, &Bs[chunk * 8]);
      }
      __syncthreads();
      #pragma unroll
      for (int ks = 0; ks < 2; ks++) {
        bf16x8 af[4], bfr[4];
        #pragma unroll
        for (int i = 0; i < 4; i++) {
          int row = wm * 64 + i * 16 + l15;
          af[i] = *(const bf16x8*)&As[row * 64 + (((ks * 4 + q) ^ (row & 7)) * 8)];
        }
        #pragma unroll
        for (int j = 0; j < 4; j++) {
          int row = wn * 64 + j * 16 + l15;
          bfr[j] = *(const bf16x8*)&Bs[row * 64 + (((ks * 4 + q) ^ (row & 7)) * 8)];
        }
        #pragma unroll
        for (int i = 0; i < 4; i++)
          #pragma unroll
          for (int j = 0; j < 4; j++)
            acc[i][j] = __builtin_amdgcn_mfma_f32_16x16x32_bf16(af[i], bfr[j], acc[i][j], 0, 0, 0);
      }
      __syncthreads();
    }
  }

  float bv[4];
  #pragma unroll
  for (int j = 0; j < 4; j++) bv[j] = bias[n0 + wn * 64 + j * 16 + l15];

  #pragma unroll
  for (int i = 0; i < 4; i++) {
    #pragma unroll
    for (int r = 0; r < 4; r++) {
      int row = m0 + wm * 64 + i * 16 + q * 4 + r;
      u16* crow = C + (size_t)row * N + n0 + wn * 64 + l15;
      #pragma unroll
      for (int j = 0; j < 4; j++) {
        float v = acc[i][j][r] + bv[j];
        if (relu) v = fmaxf(v, 0.0f);
        crow[j * 16] = f2bf(v);
      }
    }
  }
}

// ---------------- fused logits + rowmax ----------------
// per block: p = blockIdx.y, 64 rows (b) x full 1024 cols (k'), K=256.
// A (pred tile 64x256) staged once in LDS; B fragments read directly from global (L2-hot).
__global__ __launch_bounds__(512, 2)
void logits_k(const u16* __restrict__ pred, const u16* __restrict__ post,
              float* __restrict__ out) {
  __shared__ u16 As[64 * 256];       // 32 KB
  __shared__ float pmax[8][64];
  const int tid = threadIdx.x;
  const int lane = tid & 63;
  const int wave = tid >> 6;
  const int q = lane >> 4;
  const int l15 = lane & 15;
  const int p = blockIdx.y;
  const int m0 = blockIdx.x * 64;
  const u16* Ap = pred + (((size_t)p * 1024 + m0) << 8);
  const u16* Bp = post + ((size_t)p << 18);

  // stage A: 64 rows x 256 cols = 2048 chunks of 16B; swizzle chunk^(row&7)
  #pragma unroll
  for (int c = 0; c < 4; c++) {
    int chunk = c * 512 + tid;   // 32 chunks per row
    int row = chunk >> 5;
    int cg = (chunk & 31) ^ (row & 7);
    gl_lds16(Ap + row * 256 + cg * 8, &As[chunk * 8]);
  }

  f32x4 acc[4][8];
  #pragma unroll
  for (int i = 0; i < 4; i++)
    #pragma unroll
    for (int j = 0; j < 8; j++) acc[i][j] = (f32x4)(0.0f);

  __syncthreads();

  const int nbase = wave * 128;
  #pragma unroll
  for (int kt = 0; kt < 8; kt++) {
    bf16x8 bfr[8];
    #pragma unroll
    for (int j = 0; j < 8; j++) {
      int n = nbase + j * 16 + l15;
      bfr[j] = *(const bf16x8*)&Bp[(size_t)n * 256 + kt * 32 + q * 8];
    }
    bf16x8 afr[4];
    #pragma unroll
    for (int i = 0; i < 4; i++) {
      int row = i * 16 + l15;
      afr[i] = *(const bf16x8*)&As[row * 256 + ((((kt << 2) + q) ^ (row & 7)) * 8)];
    }
    #pragma unroll
    for (int i = 0; i < 4; i++)
      #pragma unroll
      for (int j = 0; j < 8; j++)
        acc[i][j] = __builtin_amdgcn_mfma_f32_16x16x32_bf16(afr[i], bfr[j], acc[i][j], 0, 0, 0);
  }

  // rowmax: per-lane over 8 n-tiles, then across the 16 col-lanes, then across waves
  float rm[4][4];
  #pragma unroll
  for (int i = 0; i < 4; i++)
    #pragma unroll
    for (int r = 0; r < 4; r++) {
      float m = acc[i][0][r];
      #pragma unroll
      for (int j = 1; j < 8; j++) m = fmaxf(m, acc[i][j][r]);
      m = fmaxf(m, __shfl_xor(m, 1, 64));
      m = fmaxf(m, __shfl_xor(m, 2, 64));
      m = fmaxf(m, __shfl_xor(m, 4, 64));
      m = fmaxf(m, __shfl_xor(m, 8, 64));
      rm[i][r] = m;
    }
  if (l15 == 0) {
    #pragma unroll
    for (int i = 0; i < 4; i++)
      #pragma unroll
      for (int r = 0; r < 4; r++) pmax[wave][i * 16 + q * 4 + r] = rm[i][r];
  }
  __syncthreads();
  #pragma unroll
  for (int i = 0; i < 4; i++)
    #pragma unroll
    for (int r = 0; r < 4; r++) {
      int row = i * 16 + q * 4 + r;
      float m = pmax[0][row];
      #pragma unroll
      for (int w = 1; w < 8; w++) m = fmaxf(m, pmax[w][row]);
      rm[i][r] = m;
    }

  float* ob = out + ((size_t)p << 20) + (size_t)m0 * 1024 + nbase + l15;
  #pragma unroll
  for (int i = 0; i < 4; i++)
    #pragma unroll
    for (int r = 0; r < 4; r++) {
      float* orow = ob + (size_t)(i * 16 + q * 4 + r) * 1024;
      #pragma unroll
      for (int j = 0; j < 8; j++) orow[j * 16] = acc[i][j][r] - rm[i][r];
    }
}

// ---------------- launch ----------------

extern "C" void kernel_launch(void* const* d_in, const int* in_sizes, int n_in,
                              void* d_out, int out_size, void* d_ws, size_t ws_size,
                              hipStream_t stream) {
  const float* anchor   = (const float*)d_in[0];
  const float* positive = (const float*)d_in[1];
  const float* W1       = (const float*)d_in[2];
  const float* b1       = (const float*)d_in[3];
  const float* W2       = (const float*)d_in[4];
  const float* b2       = (const float*)d_in[5];
  const float* Ww       = (const float*)d_in[6];
  float* out = (float*)d_out;
  char* ws = (char*)d_ws;

  u16*   A_t    = (u16*)(ws + 0x00000000);  // 32 MB  [64][1024][256] bf16
  u16*   Pos_t  = (u16*)(ws + 0x02000000);  // 32 MB
  u16*   hidden = (u16*)(ws + 0x04000000);  // 64 MB  [65536][512] bf16
  u16*   pred   = (u16*)(ws + 0x08000000);  // 32 MB  [64][1024][256] bf16
  u16*   W1b    = (u16*)(ws + 0x0A000000);  // 256 KB
  u16*   Wwb    = (u16*)(ws + 0x0A100000);  // 128 KB
  u16*   W2pb   = (u16*)(ws + 0x0A200000);  // 512 KB
  float* b2p    = (float*)(ws + 0x0A300000);

  cvt_bf16<<<512, 256, 0, stream>>>(W1, W1b, 512 * 256);
  cvt_bf16<<<256, 256, 0, stream>>>(Ww, Wwb, 256 * 256);
  w2p_kernel<<<512, 256, 0, stream>>>(Ww, W2, b2, W2pb, b2p);
  transpose_cvt<<<1024, 256, 0, stream>>>(anchor, A_t);
  transpose_cvt<<<1024, 256, 0, stream>>>(positive, Pos_t);

  // hidden = relu(A_t @ W1^T + b1): M=65536, N=512, K=256
  gemm_bt<<<dim3(4, 512), 256, 0, stream>>>(A_t, W1b, 256, nullptr, nullptr, 0,
                                            b1, hidden, 512, 1);
  // pred = A_t @ Ww^T + hidden @ W2p^T + b2p: M=65536, N=256
  gemm_bt<<<dim3(2, 512), 256, 0, stream>>>(A_t, Wwb, 256, hidden, W2pb, 512,
                                            b2p, pred, 256, 0);
  // logits + rowmax
  logits_k<<<dim3(16, 64), 512, 0, stream>>>(pred, Pos_t, out);
}

// Round 2
// 577.908 us; speedup vs baseline: 1.1100x; 1.1100x over previous
//
#include <hip/hip_runtime.h>

typedef unsigned short u16;
typedef short bf16x8 __attribute__((ext_vector_type(8)));
typedef float f32x4 __attribute__((ext_vector_type(4)));

__device__ inline u16 f2bf(float f) {
  unsigned u = __float_as_uint(f);
  u += 0x7fff + ((u >> 16) & 1);
  return (u16)(u >> 16);
}

__device__ inline void gl_lds16(const u16* g, u16* l) {
  __builtin_amdgcn_global_load_lds((const __attribute__((address_space(1))) void*)g,
                                   (__attribute__((address_space(3))) void*)l, 16, 0, 0);
}

// ---------------- prep kernels ----------------

__global__ __launch_bounds__(256) void cvt_bf16(const float* __restrict__ in,
                                                u16* __restrict__ outp, int n) {
  int i = blockIdx.x * 256 + threadIdx.x;
  if (i < n) outp[i] = f2bf(in[i]);
}

// W2p[d][h] = sum_c Ww[d][c] * W2[c][h]  (d<256, h<512); b2p[d] = sum_c Ww[d][c]*b2[c]
__global__ __launch_bounds__(256) void w2p_kernel(const float* __restrict__ Ww,
                                                  const float* __restrict__ W2,
                                                  const float* __restrict__ b2,
                                                  u16* __restrict__ W2p,
                                                  float* __restrict__ b2p) {
  int g = blockIdx.x * 256 + threadIdx.x;  // 131072 threads
  int d = g >> 9, h = g & 511;
  float s = 0.f;
  for (int c = 0; c < 256; c++) s += Ww[d * 256 + c] * W2[c * 512 + h];
  W2p[g] = f2bf(s);
  if (g < 256) {
    float t = 0.f;
    for (int c = 0; c < 256; c++) t += Ww[g * 256 + c] * b2[c];
    b2p[g] = t;
  }
}

// in: [1024 b][256 c][64 p] fp32  ->  out: [64 p][1024 b][256 c] bf16
// LDS transpose per b: coalesced float4 reads, XOR-swizzled 32KB bf16 tile,
// coalesced 16B global stores (512B contiguous per half-wave).
__global__ __launch_bounds__(256) void transpose_cvt(const float* __restrict__ in,
                                                     u16* __restrict__ outp) {
  __shared__ u16 T[64 * 256];  // 32 KB, chunk-swizzled: chunk(p,cc) = p*32 + (cc ^ ((p>>2)&15))
  const int b = blockIdx.x;
  const int tid = threadIdx.x;
  const float4* in4 = (const float4*)in + (size_t)b * 4096;

  #pragma unroll
  for (int i = 0; i < 16; i++) {
    int local = i * 256 + tid;
    int c = local >> 4;            // 0..255
    int p4 = (local & 15) << 2;    // 0..60
    float4 v = in4[local];
    int cc = c >> 3, co = c & 7;
    #pragma unroll
    for (int k = 0; k < 4; k++) {
      int p = p4 + k;
      int chunk = p * 32 + (cc ^ ((p >> 2) & 15));
      float f = (k == 0) ? v.x : (k == 1) ? v.y : (k == 2) ? v.z : v.w;
      T[chunk * 8 + co] = f2bf(f);
    }
  }
  __syncthreads();

  u16* ob = outp + (size_t)b * 256;
  #pragma unroll
  for (int j = 0; j < 8; j++) {
    int idx = j * 256 + tid;       // chunk id: 32 chunks per row
    int row = idx >> 5;            // p
    int col16 = idx & 31;          // cc
    int chunk = row * 32 + (col16 ^ ((row >> 2) & 15));
    bf16x8 vv = *(const bf16x8*)&T[chunk * 8];
    *(bf16x8*)&ob[((size_t)row << 18) + col16 * 8] = vv;
  }
}

// ---------------- generic bf16 GEMM: C = epi(A1@B1^T + A2@B2^T + bias) ----------------
// A: [M][K] bf16 row-major (stride K), B: [N][K] bf16 row-major (stride K).
// 128x128 tile, BK=64, 256 threads (4 waves, 2x2 of 64x64), 16x16x32 MFMA.
__global__ __launch_bounds__(256, 3)
void gemm_bt(const u16* __restrict__ A1, const u16* __restrict__ B1, int K1len,
             const u16* __restrict__ A2, const u16* __restrict__ B2, int K2len,
             const float* __restrict__ bias, u16* __restrict__ C, int N, int relu) {
  __shared__ u16 As[128 * 64];
  __shared__ u16 Bs[128 * 64];
  const int tid = threadIdx.x;
  const int lane = tid & 63;
  const int wave = tid >> 6;
  const int wm = wave & 1;
  const int wn = wave >> 1;
  const int m0 = blockIdx.y * 128;
  const int n0 = blockIdx.x * 128;
  const int q = lane >> 4;
  const int l15 = lane & 15;

  f32x4 acc[4][4];
  #pragma unroll
  for (int i = 0; i < 4; i++)
    #pragma unroll
    for (int j = 0; j < 4; j++) acc[i][j] = (f32x4)(0.0f);

  for (int seg = 0; seg < 2; seg++) {
    const u16* A = seg ? A2 : A1;
    const u16* B = seg ? B2 : B1;
    const int K = seg ? K2len : K1len;
    const int nkt = K >> 6;
    for (int kt = 0; kt < nkt; kt++) {
      // stage 128x64 A and B tiles; LDS chunk (row, c) holds global chunk c^(row&7)
      #pragma unroll
      for (int c = 0; c < 4; c++) {
        int chunk = c * 256 + tid;     // 0..1023 ; 8 chunks of 16B per row
        int row = chunk >> 3;
        int cg = (chunk & 7) ^ (row & 7);
        gl_lds16(A + (size_t)(m0 + row) * K + kt * 64 + cg * 8, &As[chunk * 8]);
        gl_lds16(B + (size_t)(n0 + row) * K + kt * 64 + cg * 8, &Bs[chunk * 8]);
      }
      __syncthreads();
      #pragma unroll
      for (int ks = 0; ks < 2; ks++) {
        bf16x8 af[4], bfr[4];
        #pragma unroll
        for (int i = 0; i < 4; i++) {
          int row = wm * 64 + i * 16 + l15;
          af[i] = *(const bf16x8*)&As[row * 64 + (((ks * 4 + q) ^ (row & 7)) * 8)];
        }
        #pragma unroll
        for (int j = 0; j < 4; j++) {
          int row = wn * 64 + j * 16 + l15;
          bfr[j] = *(const bf16x8*)&Bs[row * 64 + (((ks * 4 + q) ^ (row & 7)) * 8)];
        }
        #pragma unroll
        for (int i = 0; i < 4; i++)
          #pragma unroll
          for (int j = 0; j < 4; j++)
            acc[i][j] = __builtin_amdgcn_mfma_f32_16x16x32_bf16(af[i], bfr[j], acc[i][j], 0, 0, 0);
      }
      __syncthreads();
    }
  }

  float bv[4];
  #pragma unroll
  for (int j = 0; j < 4; j++) bv[j] = bias[n0 + wn * 64 + j * 16 + l15];

  #pragma unroll
  for (int i = 0; i < 4; i++) {
    #pragma unroll
    for (int r = 0; r < 4; r++) {
      int row = m0 + wm * 64 + i * 16 + q * 4 + r;
      u16* crow = C + (size_t)row * N + n0 + wn * 64 + l15;
      #pragma unroll
      for (int j = 0; j < 4; j++) {
        float v = acc[i][j][r] + bv[j];
        if (relu) v = fmaxf(v, 0.0f);
        crow[j * 16] = f2bf(v);
      }
    }
  }
}

// ---------------- fused logits + rowmax ----------------
// per block: p = blockIdx.y, 64 rows (b) x full 1024 cols (k'), K=256.
// A (pred tile 64x256) staged once in LDS; B fragments read directly from global (L2-hot).
__global__ __launch_bounds__(512, 2)
void logits_k(const u16* __restrict__ pred, const u16* __restrict__ post,
              float* __restrict__ out) {
  __shared__ u16 As[64 * 256];       // 32 KB
  __shared__ float pmax[8][64];
  const int tid = threadIdx.x;
  const int lane = tid & 63;
  const int wave = tid >> 6;
  const int q = lane >> 4;
  const int l15 = lane & 15;
  const int p = blockIdx.y;
  const int m0 = blockIdx.x * 64;
  const u16* Ap = pred + (((size_t)p * 1024 + m0) << 8);
  const u16* Bp = post + ((size_t)p << 18);

  // stage A: 64 rows x 256 cols = 2048 chunks of 16B; swizzle chunk^(row&7)
  #pragma unroll
  for (int c = 0; c < 4; c++) {
    int chunk = c * 512 + tid;   // 32 chunks per row
    int row = chunk >> 5;
    int cg = (chunk & 31) ^ (row & 7);
    gl_lds16(Ap + row * 256 + cg * 8, &As[chunk * 8]);
  }

  f32x4 acc[4][8];
  #pragma unroll
  for (int i = 0; i < 4; i++)
    #pragma unroll
    for (int j = 0; j < 8; j++) acc[i][j] = (f32x4)(0.0f);

  __syncthreads();

  const int nbase = wave * 128;
  #pragma unroll
  for (int kt = 0; kt < 8; kt++) {
    bf16x8 bfr[8];
    #pragma unroll
    for (int j = 0; j < 8; j++) {
      int n = nbase + j * 16 + l15;
      bfr[j] = *(const bf16x8*)&Bp[(size_t)n * 256 + kt * 32 + q * 8];
    }
    bf16x8 afr[4];
    #pragma unroll
    for (int i = 0; i < 4; i++) {
      int row = i * 16 + l15;
      afr[i] = *(const bf16x8*)&As[row * 256 + ((((kt << 2) + q) ^ (row & 7)) * 8)];
    }
    #pragma unroll
    for (int i = 0; i < 4; i++)
      #pragma unroll
      for (int j = 0; j < 8; j++)
        acc[i][j] = __builtin_amdgcn_mfma_f32_16x16x32_bf16(afr[i], bfr[j], acc[i][j], 0, 0, 0);
  }

  // rowmax: per-lane over 8 n-tiles, then across the 16 col-lanes, then across waves
  float rm[4][4];
  #pragma unroll
  for (int i = 0; i < 4; i++)
    #pragma unroll
    for (int r = 0; r < 4; r++) {
      float m = acc[i][0][r];
      #pragma unroll
      for (int j = 1; j < 8; j++) m = fmaxf(m, acc[i][j][r]);
      m = fmaxf(m, __shfl_xor(m, 1, 64));
      m = fmaxf(m, __shfl_xor(m, 2, 64));
      m = fmaxf(m, __shfl_xor(m, 4, 64));
      m = fmaxf(m, __shfl_xor(m, 8, 64));
      rm[i][r] = m;
    }
  if (l15 == 0) {
    #pragma unroll
    for (int i = 0; i < 4; i++)
      #pragma unroll
      for (int r = 0; r < 4; r++) pmax[wave][i * 16 + q * 4 + r] = rm[i][r];
  }
  __syncthreads();
  #pragma unroll
  for (int i = 0; i < 4; i++)
    #pragma unroll
    for (int r = 0; r < 4; r++) {
      int row = i * 16 + q * 4 + r;
      float m = pmax[0][row];
      #pragma unroll
      for (int w = 1; w < 8; w++) m = fmaxf(m, pmax[w][row]);
      rm[i][r] = m;
    }

  float* ob = out + ((size_t)p << 20) + (size_t)m0 * 1024 + nbase + l15;
  #pragma unroll
  for (int i = 0; i < 4; i++)
    #pragma unroll
    for (int r = 0; r < 4; r++) {
      float* orow = ob + (size_t)(i * 16 + q * 4 + r) * 1024;
      #pragma unroll
      for (int j = 0; j < 8; j++) orow[j * 16] = acc[i][j][r] - rm[i][r];
    }
}

// ---------------- launch ----------------

extern "C" void kernel_launch(void* const* d_in, const int* in_sizes, int n_in,
                              void* d_out, int out_size, void* d_ws, size_t ws_size,
                              hipStream_t stream) {
  const float* anchor   = (const float*)d_in[0];
  const float* positive = (const float*)d_in[1];
  const float* W1       = (const float*)d_in[2];
  const float* b1       = (const float*)d_in[3];
  const float* W2       = (const float*)d_in[4];
  const float* b2       = (const float*)d_in[5];
  const float* Ww       = (const float*)d_in[6];
  float* out = (float*)d_out;
  char* ws = (char*)d_ws;

  u16*   A_t    = (u16*)(ws + 0x00000000);  // 32 MB  [64][1024][256] bf16
  u16*   Pos_t  = (u16*)(ws + 0x02000000);  // 32 MB
  u16*   hidden = (u16*)(ws + 0x04000000);  // 64 MB  [65536][512] bf16
  u16*   pred   = (u16*)(ws + 0x08000000);  // 32 MB  [64][1024][256] bf16
  u16*   W1b    = (u16*)(ws + 0x0A000000);  // 256 KB
  u16*   Wwb    = (u16*)(ws + 0x0A100000);  // 128 KB
  u16*   W2pb   = (u16*)(ws + 0x0A200000);  // 512 KB
  float* b2p    = (float*)(ws + 0x0A300000);

  cvt_bf16<<<512, 256, 0, stream>>>(W1, W1b, 512 * 256);
  cvt_bf16<<<256, 256, 0, stream>>>(Ww, Wwb, 256 * 256);
  w2p_kernel<<<512, 256, 0, stream>>>(Ww, W2, b2, W2pb, b2p);
  transpose_cvt<<<1024, 256, 0, stream>>>(anchor, A_t);
  transpose_cvt<<<1024, 256, 0, stream>>>(positive, Pos_t);

  // hidden = relu(A_t @ W1^T + b1): M=65536, N=512, K=256
  gemm_bt<<<dim3(4, 512), 256, 0, stream>>>(A_t, W1b, 256, nullptr, nullptr, 0,
                                            b1, hidden, 512, 1);
  // pred = A_t @ Ww^T + hidden @ W2p^T + b2p: M=65536, N=256
  gemm_bt<<<dim3(2, 512), 256, 0, stream>>>(A_t, Wwb, 256, hidden, W2pb, 512,
                                            b2p, pred, 256, 0);
  // logits + rowmax
  logits_k<<<dim3(16, 64), 512, 0, stream>>>(pred, Pos_t, out);
}